// Round 17
// baseline (839.559 us; speedup 1.0000x reference)
//
#include <hip/hip_runtime.h>
#include <hip/hip_bf16.h>
#include <math.h>

#define KD 1024
#define VD 50000
#define BD 2048
#define WDIM 20
#define NE (BD * WDIM)     /* 40960 entries */
#define THRV 1e-10f
#define PI_F 3.14159274101257324f  /* 0x40490FDB — f32(pi) */

#define CHV   12288        /* v's per chunk (96 KB) */
#define NCHV  5            /* 4 full + tail */
#define TAILV 848          /* 50000 - 4*12288 */
#define CAPE  11264        /* term buffer capacity; E[entries/chunk]=10067, +13 sigma */

// d_out is FLOAT32[2049]: [0..2048) = mu (as float), [2048] = E.
//
// LESSONS: (r8-r10) asm/global_load_lds spills per-thread arrays; (r13) 1024-thr
// cap is 128 VGPR; (r14) staged-gather match loop at 2 waves/SIMD is latency-
// bound (~30% VALUBusy). This round: CSR scatter — flat per-entry term loop
// (load-balanced, ILP-rich), terms staged in LDS, gathered to phi regs by eidx.
// (r15/r16 were infra failures on a dead pod — identical kernel, 3rd submit.)

// ---------------------------------------------------------------------------
// K1: zero the bin counters (runs every call — buffers must be rebuilt).
// ---------------------------------------------------------------------------
__global__ void zero_kernel(unsigned int* bins) {
    if (threadIdx.x < 24) bins[threadIdx.x] = 0;   // bincnt[8],binbase[8],bincur[8]
}

// ---------------------------------------------------------------------------
// K2: trig tables + bin histogram. cst[w][b] = (cos,sin)(pi*pos[b][w]).
// Same trig ops as all passing rounds -> bit-identical terms.
// ---------------------------------------------------------------------------
__global__ __launch_bounds__(256) void prep_kernel(
    const float* __restrict__ pos,
    const int*   __restrict__ ids,
    float2* __restrict__ cst,
    unsigned int* __restrict__ bincnt)
{
    const int b = blockIdx.x * 256 + threadIdx.x;
    if (b >= BD) return;
#pragma unroll
    for (int w = 0; w < WDIM; ++w) {
        const int id = ids[b * WDIM + w];
        const float pf = __fmul_rn(pos[b * WDIM + w], PI_F);
        cst[w * BD + b] = make_float2(cosf(pf), sinf(pf));
        atomicAdd(&bincnt[id / CHV], 1u);
    }
}

// ---------------------------------------------------------------------------
// K3: exclusive scan of 5 bins + zero cursors (1 thread).
// ---------------------------------------------------------------------------
__global__ void scan_kernel(const unsigned int* __restrict__ bincnt,
                            unsigned int* __restrict__ binbase,
                            unsigned int* __restrict__ bincur)
{
    if (threadIdx.x == 0 && blockIdx.x == 0) {
        unsigned int s = 0;
        for (int c = 0; c < NCHV; ++c) { binbase[c] = s; s += bincnt[c]; }
        binbase[NCHV] = s;
        for (int c = 0; c < NCHV; ++c) bincur[c] = 0;
    }
}

// ---------------------------------------------------------------------------
// K4: scatter entries into bin-grouped order. entry = {c, s, v, pad};
// eidx[b*20+w] = slot (u16). Slot order varies across runs (atomics) but the
// output is slot-invariant: terms are written to term[slot] and read back via
// eidx — self-consistent.
// ---------------------------------------------------------------------------
__global__ __launch_bounds__(256) void scatter_kernel(
    const int* __restrict__ ids,
    const float2* __restrict__ cst,
    const unsigned int* __restrict__ binbase,
    unsigned int* __restrict__ bincur,
    float4* __restrict__ entry_buf,
    unsigned short* __restrict__ eidx)
{
    const int i = blockIdx.x * 256 + threadIdx.x;
    if (i >= NE) return;
    const int b = i / WDIM;
    const int w = i - b * WDIM;
    const int id = ids[i];
    const float2 cs = cst[w * BD + b];
    const int bin = id / CHV;
    const unsigned int pos = binbase[bin] + atomicAdd(&bincur[bin], 1u);
    entry_buf[pos] = make_float4(cs.x, cs.y, __uint_as_float((unsigned)id), 0.f);
    eidx[i] = (unsigned short)pos;
}

// ---------------------------------------------------------------------------
// K5: scores. Block = row k. Per chunk: store pf->LDS (+norm), barrier,
// prefetch next chunk, FLAT term loop (balanced), barrier, gather to phi regs,
// barrier. Tail: numpy pairwise-8 sum (bit-identical to rounds 5-14).
// ---------------------------------------------------------------------------
__global__ __launch_bounds__(512, 2) void scores_kernel(
    const float* __restrict__ W,
    const float4* __restrict__ entry_buf,
    const unsigned short* __restrict__ eidx,
    const unsigned int* __restrict__ binbase,
    float* __restrict__ norm2,
    float* __restrict__ scores)   // [KD][BD]
{
    __shared__ __align__(16) float chunk[CHV * 2];   // 96 KB
    __shared__ float term[CAPE];                     // 44 KB
    __shared__ float smr[8];

    const int t = threadIdx.x;
    const int k = blockIdx.x;
    const float* Wk = W + (size_t)k * (VD * 2);

    // per-thread eidx for b = t, t+512, t+1024, t+1536 (u16 pairs as u32)
    unsigned int idxr[4][10];
#pragma unroll
    for (int bb = 0; bb < 4; ++bb) {
        const unsigned int* p =
            reinterpret_cast<const unsigned int*>(eidx + (t + bb * 512) * WDIM);
#pragma unroll
        for (int j = 0; j < 10; ++j) idxr[bb][j] = p[j];
    }

    unsigned int base[NCHV + 1];
#pragma unroll
    for (int c = 0; c <= NCHV; ++c) base[c] = binbase[c];

    float phi[4][WDIM];
#pragma unroll
    for (int bb = 0; bb < 4; ++bb)
#pragma unroll
        for (int w = 0; w < WDIM; ++w) phi[bb][w] = 0.f;

    float nacc = 0.0f;

    // prologue: prefetch chunk 0 (12 float4/thread)
    float4 pf[12];
    {
        const float4* src = reinterpret_cast<const float4*>(Wk);
#pragma unroll
        for (int j = 0; j < 12; ++j) pf[j] = src[t + j * 512];
    }

    for (int c = 0; c < NCHV; ++c) {
        const bool istail = (c == NCHV - 1);
        const int nf4 = istail ? (TAILV * 2) / 4 : (CHV * 2) / 4;

        // A: store prefetched chunk -> LDS, accumulate norm
        float4* dst = reinterpret_cast<float4*>(chunk);
#pragma unroll
        for (int j = 0; j < 12; ++j) {
            const int i = t + j * 512;
            if (i < nf4) {
                const float4 v = pf[j];
                dst[i] = v;
                nacc += v.x * v.x + v.y * v.y + v.z * v.z + v.w * v.w;
            }
        }
        __syncthreads();   // chunk visible

        // C: prefetch next chunk (flies under D+F)
        if (!istail) {
            const int nnf4 = (c + 1 == NCHV - 1) ? (TAILV * 2) / 4 : (CHV * 2) / 4;
            const float4* src = reinterpret_cast<const float4*>(
                Wk + (size_t)(c + 1) * (CHV * 2));
#pragma unroll
            for (int j = 0; j < 12; ++j) {
                const int i = t + j * 512;
                if (i < nnf4) pf[j] = src[i];
            }
        }

        // D: flat term loop over this chunk's entries (load-balanced)
        const unsigned int b0  = base[c];
        const unsigned int cnt = base[c + 1] - b0;
        const unsigned int lim = cnt < CAPE ? cnt : CAPE;
        const int vlo = c * CHV;
        for (unsigned int e = t; e < lim; e += 512) {
            const float4 en = entry_buf[b0 + e];
            const unsigned int v = __float_as_uint(en.z);
            const float2 g = *reinterpret_cast<const float2*>(&chunk[2 * (v - vlo)]);
            const float mag = hypotf(g.x, g.y);
            const float re = __fadd_rn(__fmul_rn(g.x, en.x), __fmul_rn(g.y, en.y));
            const float im = __fsub_rn(__fmul_rn(g.y, en.x), __fmul_rn(g.x, en.y));
            term[e] = __fadd_rn(mag, fabsf(atan2f(im, re)));
        }
        __syncthreads();   // terms visible

        // F: gather this chunk's terms into phi registers
#pragma unroll
        for (int bb = 0; bb < 4; ++bb) {
#pragma unroll
            for (int w = 0; w < WDIM; ++w) {
                const unsigned int ide =
                    (idxr[bb][w >> 1] >> ((w & 1) * 16)) & 0xFFFFu;
                const unsigned int rel = ide - b0;
                if (rel < lim) phi[bb][w] = term[rel];
            }
        }
        __syncthreads();   // gathers done before next A/D overwrite LDS
    }

    // norm2 reduce (one block per row — sole writer)
#pragma unroll
    for (int off = 32; off > 0; off >>= 1) nacc += __shfl_down(nacc, off, 64);
    if ((t & 63) == 0) smr[t >> 6] = nacc;
    __syncthreads();
    if (t == 0) {
        float s = 0.0f;
#pragma unroll
        for (int i = 0; i < 8; ++i) s += smr[i];
        norm2[k] = s;
    }

    // score tail: exact numpy pairwise-8 order per b
#pragma unroll
    for (int bb = 0; bb < 4; ++bb) {
        const int b = t + bb * 512;
        const float r0 = __fadd_rn(phi[bb][0], phi[bb][8]);
        const float r1 = __fadd_rn(phi[bb][1], phi[bb][9]);
        const float r2 = __fadd_rn(phi[bb][2], phi[bb][10]);
        const float r3 = __fadd_rn(phi[bb][3], phi[bb][11]);
        const float r4 = __fadd_rn(phi[bb][4], phi[bb][12]);
        const float r5 = __fadd_rn(phi[bb][5], phi[bb][13]);
        const float r6 = __fadd_rn(phi[bb][6], phi[bb][14]);
        const float r7 = __fadd_rn(phi[bb][7], phi[bb][15]);
        float score = __fadd_rn(__fadd_rn(__fadd_rn(r0, r1), __fadd_rn(r2, r3)),
                                __fadd_rn(__fadd_rn(r4, r5), __fadd_rn(r6, r7)));
        score = __fadd_rn(score, phi[bb][16]);
        score = __fadd_rn(score, phi[bb][17]);
        score = __fadd_rn(score, phi[bb][18]);
        score = __fadd_rn(score, phi[bb][19]);
        scores[(size_t)k * BD + b] = score;
    }
}

// ---------------------------------------------------------------------------
// argmax over k per batch (coalesced). Strict >, tie -> smallest k.
// ---------------------------------------------------------------------------
__global__ __launch_bounds__(256) void argmax_kernel(
    const float* __restrict__ scores,
    float* __restrict__ out,
    int*   __restrict__ mu_int)
{
    const int b = blockIdx.x * 256 + threadIdx.x;
    float best = -3.402823466e+38f;
    int   bi   = 0;
    for (int k = 0; k < KD; ++k) {
        const float v = scores[(size_t)k * BD + b];
        if (v > best) { best = v; bi = k; }
    }
    mu_int[b] = bi;
    out[b] = (float)bi;
}

// ---------------------------------------------------------------------------
// per-batch energy contribution
// ---------------------------------------------------------------------------
__global__ __launch_bounds__(64) void e_kernel(
    const float* __restrict__ W,
    const float* __restrict__ Ps,
    const float* __restrict__ pos,
    const int*   __restrict__ ids,
    const int*   __restrict__ mu_int,
    const float* __restrict__ norm2,
    float* __restrict__ contrib)
{
    const int b = blockIdx.x;
    const int t = threadIdx.x;
    const int mu = mu_int[b];
    const float* Wm = W + (size_t)mu * (VD * 2);

    float loc_abs = 0.0f, loc_phi = 0.0f;
    if (t < WDIM) {
        const int id = ids[b * WDIM + t];
        const float P = Ps[b * WDIM + t];
        const float pf = __fmul_rn(pos[b * WDIM + t], PI_F);
        const float c = cosf(pf), s = sinf(pf);
        const float2 g = *reinterpret_cast<const float2*>(Wm + 2 * (size_t)id);
        float re = P * (g.x * c + g.y * s);
        float im = P * (g.y * c - g.x * s);
        if (re < THRV && re > -THRV) re = THRV;
        if (im < THRV && im > -THRV) im = THRV;
        loc_abs = sqrtf(re * re + im * im);
        loc_phi = fabsf(atan2f(im, re)) * P;
    }
#pragma unroll
    for (int off = 32; off > 0; off >>= 1) {
        loc_abs += __shfl_down(loc_abs, off, 64);
        loc_phi += __shfl_down(loc_phi, off, 64);
    }
    if (t == 0) {
        const float den = sqrtf(norm2[mu]);
        contrib[b] = loc_abs / den + loc_phi;
    }
}

// ---------------------------------------------------------------------------
// final reduction (f64 accum), E -> out[2048]
// ---------------------------------------------------------------------------
__global__ __launch_bounds__(256) void finalize_kernel(
    const float* __restrict__ contrib,
    float* __restrict__ out)
{
    __shared__ double sm[4];
    double acc = 0.0;
    for (int i = threadIdx.x; i < BD; i += 256) acc += (double)contrib[i];
#pragma unroll
    for (int off = 32; off > 0; off >>= 1) acc += __shfl_down(acc, off, 64);
    if ((threadIdx.x & 63) == 0) sm[threadIdx.x >> 6] = acc;
    __syncthreads();
    if (threadIdx.x == 0) {
        double s = sm[0] + sm[1] + sm[2] + sm[3];
        out[BD] = (float)(-s);
    }
}

// ---------------------------------------------------------------------------
// Fallback (round-5 passing path) if ws_size is too small
// ---------------------------------------------------------------------------
__global__ __launch_bounds__(1024) void scores_kernel_fb(
    const float* __restrict__ W,
    const float* __restrict__ pos,
    const int*   __restrict__ ids,
    float* __restrict__ out,
    int* __restrict__ mu_int)
{
    __shared__ int   s_id[WDIM];
    __shared__ float s_c[WDIM];
    __shared__ float s_s[WDIM];
    __shared__ float r_val[16];
    __shared__ int   r_idx[16];

    const int b = blockIdx.x;
    const int t = threadIdx.x;

    if (t < WDIM) {
        s_id[t] = ids[b * WDIM + t];
        const float pf = __fmul_rn(pos[b * WDIM + t], PI_F);
        s_c[t] = cosf(pf);
        s_s[t] = sinf(pf);
    }
    __syncthreads();

    const float* Wk = W + (size_t)t * (VD * 2);
    float phi[WDIM];
#pragma unroll
    for (int w = 0; w < WDIM; ++w) {
        const float2 g = *reinterpret_cast<const float2*>(Wk + 2 * (size_t)s_id[w]);
        const float c = s_c[w], s = s_s[w];
        const float mag = hypotf(g.x, g.y);
        const float re = __fadd_rn(__fmul_rn(g.x, c), __fmul_rn(g.y, s));
        const float im = __fsub_rn(__fmul_rn(g.y, c), __fmul_rn(g.x, s));
        phi[w] = __fadd_rn(mag, fabsf(atan2f(im, re)));
    }
    const float r0 = __fadd_rn(phi[0], phi[8]);
    const float r1 = __fadd_rn(phi[1], phi[9]);
    const float r2 = __fadd_rn(phi[2], phi[10]);
    const float r3 = __fadd_rn(phi[3], phi[11]);
    const float r4 = __fadd_rn(phi[4], phi[12]);
    const float r5 = __fadd_rn(phi[5], phi[13]);
    const float r6 = __fadd_rn(phi[6], phi[14]);
    const float r7 = __fadd_rn(phi[7], phi[15]);
    float score = __fadd_rn(__fadd_rn(__fadd_rn(r0, r1), __fadd_rn(r2, r3)),
                            __fadd_rn(__fadd_rn(r4, r5), __fadd_rn(r6, r7)));
    score = __fadd_rn(score, phi[16]);
    score = __fadd_rn(score, phi[17]);
    score = __fadd_rn(score, phi[18]);
    score = __fadd_rn(score, phi[19]);

    float v = score; int vi = t;
#pragma unroll
    for (int off = 32; off > 0; off >>= 1) {
        float ov = __shfl_down(v, off, 64);
        int   oi = __shfl_down(vi, off, 64);
        if (ov > v || (ov == v && oi < vi)) { v = ov; vi = oi; }
    }
    if ((t & 63) == 0) { r_val[t >> 6] = v; r_idx[t >> 6] = vi; }
    __syncthreads();
    if (t == 0) {
        float bv = r_val[0]; int bi = r_idx[0];
#pragma unroll
        for (int i = 1; i < 16; ++i) {
            if (r_val[i] > bv || (r_val[i] == bv && r_idx[i] < bi)) {
                bv = r_val[i]; bi = r_idx[i];
            }
        }
        mu_int[b] = bi;
        out[b] = (float)bi;
    }
}

__global__ __launch_bounds__(512) void norm_kernel_fb(
    const float* __restrict__ W,
    float* __restrict__ norm2)
{
    const int k = blockIdx.x;
    const float4* row = reinterpret_cast<const float4*>(W + (size_t)k * (VD * 2));
    const int n4 = (VD * 2) / 4;
    float acc = 0.0f;
    for (int i = threadIdx.x; i < n4; i += 512) {
        float4 v = row[i];
        acc += v.x * v.x + v.y * v.y + v.z * v.z + v.w * v.w;
    }
    __shared__ float sm[8];
#pragma unroll
    for (int off = 32; off > 0; off >>= 1) acc += __shfl_down(acc, off, 64);
    if ((threadIdx.x & 63) == 0) sm[threadIdx.x >> 6] = acc;
    __syncthreads();
    if (threadIdx.x == 0) {
        float s = 0.0f;
#pragma unroll
        for (int i = 0; i < 8; ++i) s += sm[i];
        norm2[k] = s;
    }
}

extern "C" void kernel_launch(void* const* d_in, const int* in_sizes, int n_in,
                              void* d_out, int out_size, void* d_ws, size_t ws_size,
                              hipStream_t stream) {
    const float* W   = (const float*)d_in[0];  // (K, V, 2) fp32
    const float* Ps  = (const float*)d_in[1];  // (B, WD) fp32
    const float* pos = (const float*)d_in[2];  // (B, WD) fp32
    const int*   ids = (const int*)d_in[3];    // (B, WD) int32

    float* out = (float*)d_out;                // float32[2049]

    // ws layout (16B alignment first)
    char* p = (char*)d_ws;
    float4*         entry_buf = (float4*)p;                 p += (size_t)NE * 16;       // 655,360
    float2*         cst       = (float2*)p;                 p += (size_t)NE * 8;        // 327,680
    float*          scores    = (float*)p;                  p += (size_t)KD * BD * 4;   // 8,388,608
    unsigned short* eidx      = (unsigned short*)p;         p += (size_t)NE * 2;        // 81,920
    unsigned int*   bins      = (unsigned int*)p;           p += 24 * 4;                // bincnt[8],binbase[8],bincur[8]
    float*          norm2     = (float*)p;                  p += KD * 4;
    float*          contrib   = (float*)p;                  p += BD * 4;
    int*            mu_int    = (int*)p;                    p += BD * 4;
    const size_t need = (size_t)(p - (char*)d_ws);

    unsigned int* bincnt  = bins;
    unsigned int* binbase = bins + 8;
    unsigned int* bincur  = bins + 16;

    if (ws_size >= need) {
        zero_kernel<<<1, 64, 0, stream>>>(bins);
        prep_kernel<<<(BD + 255) / 256, 256, 0, stream>>>(pos, ids, cst, bincnt);
        scan_kernel<<<1, 64, 0, stream>>>(bincnt, binbase, bincur);
        scatter_kernel<<<(NE + 255) / 256, 256, 0, stream>>>(
            ids, cst, binbase, bincur, entry_buf, eidx);
        scores_kernel<<<KD, 512, 0, stream>>>(
            W, entry_buf, eidx, binbase, norm2, scores);
        argmax_kernel<<<BD / 256, 256, 0, stream>>>(scores, out, mu_int);
    } else {
        scores_kernel_fb<<<BD, 1024, 0, stream>>>(W, pos, ids, out, mu_int);
        norm_kernel_fb<<<KD, 512, 0, stream>>>(W, norm2);
    }
    e_kernel<<<BD, 64, 0, stream>>>(W, Ps, pos, ids, mu_int, norm2, contrib);
    finalize_kernel<<<1, 256, 0, stream>>>(contrib, out);
}

// Round 18
// 182.668 us; speedup vs baseline: 4.5961x; 4.5961x over previous
//
#include <hip/hip_runtime.h>
#include <hip/hip_bf16.h>
#include <math.h>

#define KD 1024
#define VD 50000
#define BD 2048
#define WDIM 20
#define THRV 1e-10f
#define PI_F 3.14159274101257324f  /* 0x40490FDB — f32(pi) */

#define NCHUNK 4
#define CHUNK 12500              /* complex elements per chunk; 4*12500 = VD */

// d_out is FLOAT32[2049]: [0..2048) = mu (as float), [2048] = E.
//
// Round-18: r7 structure (proven best, 222.6us, VGPR 64, no spill) + fused
// argmax via packed-u64 atomicMax (scores>0 -> f32 bits monotonic; low word
// KD-1-k makes ties pick smallest k, matching stable argsort). Removes the
// 8.4MB scores write + argmax kernel. amax re-zeroed every call (0xAA poison
// would win the max otherwise). Everything else byte-identical to r7.

// ---------------------------------------------------------------------------
// Kernel P: b-minor tables. cst[w][b]=(cos,sin)(pi*pos[b][w]);
// idp[j][b] = ids[b][2j] | ids[b][2j+1]<<16. Same trig ops as passing rounds.
// ---------------------------------------------------------------------------
__global__ __launch_bounds__(256) void prep_kernel(
    const float* __restrict__ pos,
    const int*   __restrict__ ids,
    float2* __restrict__ cst,
    unsigned int* __restrict__ idp)
{
    const int b = blockIdx.x * 256 + threadIdx.x;
    if (b >= BD) return;
    int idv[WDIM];
#pragma unroll
    for (int w = 0; w < WDIM; ++w) {
        idv[w] = ids[b * WDIM + w];
        const float pf = __fmul_rn(pos[b * WDIM + w], PI_F);
        cst[w * BD + b] = make_float2(cosf(pf), sinf(pf));
    }
#pragma unroll
    for (int j = 0; j < WDIM / 2; ++j)
        idp[j * BD + b] = (unsigned int)idv[2 * j] |
                          ((unsigned int)idv[2 * j + 1] << 16);
}

// ---------------------------------------------------------------------------
// zero the 2048 u64 argmax accumulators (every call — ws is poisoned 0xAA)
// ---------------------------------------------------------------------------
__global__ __launch_bounds__(256) void zero64_kernel(unsigned long long* amax) {
    const int i = blockIdx.x * 256 + threadIdx.x;
    if (i < BD) amax[i] = 0ull;
}

// ---------------------------------------------------------------------------
// Kernel B (r7 body): one block per W row k. Stream the row through LDS in 4
// chunks (coalesced; W read once; norm2 fused). Gathers are LDS reads; the
// divergent chunk-match phase only COPIES float2 -> registers; hypot/atan2
// runs once afterwards, divergence-free, exact numpy pairwise-8 order.
// Epilogue: packed-u64 atomicMax instead of scores-store.
// ---------------------------------------------------------------------------
__global__ __launch_bounds__(1024, 4) void row_kernel(
    const float* __restrict__ W,
    const unsigned int* __restrict__ idp,
    const float2* __restrict__ cst,
    float* __restrict__ norm2,
    unsigned long long* __restrict__ amax)
{
    __shared__ __align__(16) float chunk[CHUNK * 2];   // 100 KB
    __shared__ float sm[16];

    const int k = blockIdx.x;
    const int t = threadIdx.x;
    const float* Wk = W + (size_t)k * (VD * 2);

    // per-thread ids for b = t and b = t + 1024 (packed u16 pairs)
    unsigned int idreg[2][WDIM / 2];
#pragma unroll
    for (int j = 0; j < WDIM / 2; ++j) {
        idreg[0][j] = idp[j * BD + t];
        idreg[1][j] = idp[j * BD + t + 1024];
    }

    float gx[2][WDIM], gy[2][WDIM];
#pragma unroll
    for (int w = 0; w < WDIM; ++w) {
        gx[0][w] = 0.f; gy[0][w] = 0.f; gx[1][w] = 0.f; gy[1][w] = 0.f;
    }

    float nacc = 0.0f;

    for (int c = 0; c < NCHUNK; ++c) {
        __syncthreads();   // protect chunk from previous iteration's readers
        // ---- coalesced chunk stream + norm2 partial ----
        const float4* src = reinterpret_cast<const float4*>(Wk + c * (CHUNK * 2));
        float4* dst = reinterpret_cast<float4*>(chunk);
        for (int i = t; i < (CHUNK * 2) / 4; i += 1024) {
            const float4 v = src[i];
            dst[i] = v;
            nacc += v.x * v.x + v.y * v.y + v.z * v.z + v.w * v.w;
        }
        __syncthreads();

        // ---- match phase: copy g for ids inside this chunk ----
        const int lo = c * CHUNK;
#pragma unroll
        for (int bb = 0; bb < 2; ++bb) {
#pragma unroll
            for (int w = 0; w < WDIM; ++w) {
                const int id  = (int)((idreg[bb][w >> 1] >> ((w & 1) * 16)) & 0xFFFFu);
                const int off = id - lo;
                const bool m  = (unsigned)off < (unsigned)CHUNK;
                const int a   = m ? off : 0;
                const float x = chunk[2 * a];
                const float y = chunk[2 * a + 1];
                if (m) { gx[bb][w] = x; gy[bb][w] = y; }
            }
        }
    }

    // ---- norm2 block reduction ----
#pragma unroll
    for (int off = 32; off > 0; off >>= 1) nacc += __shfl_down(nacc, off, 64);
    if ((t & 63) == 0) sm[t >> 6] = nacc;
    __syncthreads();
    if (t == 0) {
        float s = 0.0f;
#pragma unroll
        for (int i = 0; i < 16; ++i) s += sm[i];
        norm2[k] = s;
    }

    // ---- score math (divergence-free), exact numpy pairwise-8 order ----
#pragma unroll
    for (int bb = 0; bb < 2; ++bb) {
        const int b = t + bb * 1024;
        float phi[WDIM];
#pragma unroll
        for (int w = 0; w < WDIM; ++w) {
            const float2 cs = cst[w * BD + b];
            const float x = gx[bb][w], y = gy[bb][w];
            const float mag = hypotf(x, y);
            const float re  = __fadd_rn(__fmul_rn(x, cs.x), __fmul_rn(y, cs.y));
            const float im  = __fsub_rn(__fmul_rn(y, cs.x), __fmul_rn(x, cs.y));
            phi[w] = __fadd_rn(mag, fabsf(atan2f(im, re)));
        }
        const float r0 = __fadd_rn(phi[0], phi[8]);
        const float r1 = __fadd_rn(phi[1], phi[9]);
        const float r2 = __fadd_rn(phi[2], phi[10]);
        const float r3 = __fadd_rn(phi[3], phi[11]);
        const float r4 = __fadd_rn(phi[4], phi[12]);
        const float r5 = __fadd_rn(phi[5], phi[13]);
        const float r6 = __fadd_rn(phi[6], phi[14]);
        const float r7 = __fadd_rn(phi[7], phi[15]);
        float score = __fadd_rn(__fadd_rn(__fadd_rn(r0, r1), __fadd_rn(r2, r3)),
                                __fadd_rn(__fadd_rn(r4, r5), __fadd_rn(r6, r7)));
        score = __fadd_rn(score, phi[16]);
        score = __fadd_rn(score, phi[17]);
        score = __fadd_rn(score, phi[18]);
        score = __fadd_rn(score, phi[19]);

        // fused argmax: score>0 so f32 bits are order-preserving; ties ->
        // larger (KD-1-k) wins = smaller k (stable argsort semantics)
        const unsigned long long packed =
            ((unsigned long long)__float_as_uint(score) << 32) |
            (unsigned long long)(unsigned)(KD - 1 - k);
        atomicMax(&amax[b], packed);
    }
}

// ---------------------------------------------------------------------------
// decode amax -> mu (out + mu_int)
// ---------------------------------------------------------------------------
__global__ __launch_bounds__(256) void decode_kernel(
    const unsigned long long* __restrict__ amax,
    float* __restrict__ out,
    int*   __restrict__ mu_int)
{
    const int b = blockIdx.x * 256 + threadIdx.x;
    if (b >= BD) return;
    const int mu = KD - 1 - (int)(amax[b] & 0xFFFFFFFFull);
    mu_int[b] = mu;
    out[b] = (float)mu;
}

// ---------------------------------------------------------------------------
// per-batch energy contribution
// ---------------------------------------------------------------------------
__global__ __launch_bounds__(64) void e_kernel(
    const float* __restrict__ W,
    const float* __restrict__ Ps,
    const float* __restrict__ pos,
    const int*   __restrict__ ids,
    const int*   __restrict__ mu_int,
    const float* __restrict__ norm2,
    float* __restrict__ contrib)
{
    const int b = blockIdx.x;
    const int t = threadIdx.x;
    const int mu = mu_int[b];
    const float* Wm = W + (size_t)mu * (VD * 2);

    float loc_abs = 0.0f, loc_phi = 0.0f;
    if (t < WDIM) {
        const int id = ids[b * WDIM + t];
        const float P = Ps[b * WDIM + t];
        const float pf = __fmul_rn(pos[b * WDIM + t], PI_F);
        const float c = cosf(pf), s = sinf(pf);
        const float2 g = *reinterpret_cast<const float2*>(Wm + 2 * (size_t)id);
        float re = P * (g.x * c + g.y * s);
        float im = P * (g.y * c - g.x * s);
        if (re < THRV && re > -THRV) re = THRV;
        if (im < THRV && im > -THRV) im = THRV;
        loc_abs = sqrtf(re * re + im * im);
        loc_phi = fabsf(atan2f(im, re)) * P;
    }
#pragma unroll
    for (int off = 32; off > 0; off >>= 1) {
        loc_abs += __shfl_down(loc_abs, off, 64);
        loc_phi += __shfl_down(loc_phi, off, 64);
    }
    if (t == 0) {
        const float den = sqrtf(norm2[mu]);
        contrib[b] = loc_abs / den + loc_phi;
    }
}

// ---------------------------------------------------------------------------
// final reduction (f64 accum), E -> out[2048]
// ---------------------------------------------------------------------------
__global__ __launch_bounds__(256) void finalize_kernel(
    const float* __restrict__ contrib,
    float* __restrict__ out)
{
    __shared__ double sm[4];
    double acc = 0.0;
    for (int i = threadIdx.x; i < BD; i += 256) acc += (double)contrib[i];
#pragma unroll
    for (int off = 32; off > 0; off >>= 1) acc += __shfl_down(acc, off, 64);
    if ((threadIdx.x & 63) == 0) sm[threadIdx.x >> 6] = acc;
    __syncthreads();
    if (threadIdx.x == 0) {
        double s = sm[0] + sm[1] + sm[2] + sm[3];
        out[BD] = (float)(-s);
    }
}

// ---------------------------------------------------------------------------
// Fallback (round-5 passing path) if ws_size is too small
// ---------------------------------------------------------------------------
__global__ __launch_bounds__(1024) void scores_kernel_fb(
    const float* __restrict__ W,
    const float* __restrict__ pos,
    const int*   __restrict__ ids,
    float* __restrict__ out,
    int* __restrict__ mu_int)
{
    __shared__ int   s_id[WDIM];
    __shared__ float s_c[WDIM];
    __shared__ float s_s[WDIM];
    __shared__ float r_val[16];
    __shared__ int   r_idx[16];

    const int b = blockIdx.x;
    const int t = threadIdx.x;

    if (t < WDIM) {
        s_id[t] = ids[b * WDIM + t];
        const float pf = __fmul_rn(pos[b * WDIM + t], PI_F);
        s_c[t] = cosf(pf);
        s_s[t] = sinf(pf);
    }
    __syncthreads();

    const float* Wk = W + (size_t)t * (VD * 2);
    float phi[WDIM];
#pragma unroll
    for (int w = 0; w < WDIM; ++w) {
        const float2 g = *reinterpret_cast<const float2*>(Wk + 2 * (size_t)s_id[w]);
        const float c = s_c[w], s = s_s[w];
        const float mag = hypotf(g.x, g.y);
        const float re = __fadd_rn(__fmul_rn(g.x, c), __fmul_rn(g.y, s));
        const float im = __fsub_rn(__fmul_rn(g.y, c), __fmul_rn(g.x, s));
        phi[w] = __fadd_rn(mag, fabsf(atan2f(im, re)));
    }
    const float r0 = __fadd_rn(phi[0], phi[8]);
    const float r1 = __fadd_rn(phi[1], phi[9]);
    const float r2 = __fadd_rn(phi[2], phi[10]);
    const float r3 = __fadd_rn(phi[3], phi[11]);
    const float r4 = __fadd_rn(phi[4], phi[12]);
    const float r5 = __fadd_rn(phi[5], phi[13]);
    const float r6 = __fadd_rn(phi[6], phi[14]);
    const float r7 = __fadd_rn(phi[7], phi[15]);
    float score = __fadd_rn(__fadd_rn(__fadd_rn(r0, r1), __fadd_rn(r2, r3)),
                            __fadd_rn(__fadd_rn(r4, r5), __fadd_rn(r6, r7)));
    score = __fadd_rn(score, phi[16]);
    score = __fadd_rn(score, phi[17]);
    score = __fadd_rn(score, phi[18]);
    score = __fadd_rn(score, phi[19]);

    float v = score; int vi = t;
#pragma unroll
    for (int off = 32; off > 0; off >>= 1) {
        float ov = __shfl_down(v, off, 64);
        int   oi = __shfl_down(vi, off, 64);
        if (ov > v || (ov == v && oi < vi)) { v = ov; vi = oi; }
    }
    if ((t & 63) == 0) { r_val[t >> 6] = v; r_idx[t >> 6] = vi; }
    __syncthreads();
    if (t == 0) {
        float bv = r_val[0]; int bi = r_idx[0];
#pragma unroll
        for (int i = 1; i < 16; ++i) {
            if (r_val[i] > bv || (r_val[i] == bv && r_idx[i] < bi)) {
                bv = r_val[i]; bi = r_idx[i];
            }
        }
        mu_int[b] = bi;
        out[b] = (float)bi;
    }
}

__global__ __launch_bounds__(512) void norm_kernel_fb(
    const float* __restrict__ W,
    float* __restrict__ norm2)
{
    const int k = blockIdx.x;
    const float4* row = reinterpret_cast<const float4*>(W + (size_t)k * (VD * 2));
    const int n4 = (VD * 2) / 4;
    float acc = 0.0f;
    for (int i = threadIdx.x; i < n4; i += 512) {
        float4 v = row[i];
        acc += v.x * v.x + v.y * v.y + v.z * v.z + v.w * v.w;
    }
    __shared__ float sm[8];
#pragma unroll
    for (int off = 32; off > 0; off >>= 1) acc += __shfl_down(acc, off, 64);
    if ((threadIdx.x & 63) == 0) sm[threadIdx.x >> 6] = acc;
    __syncthreads();
    if (threadIdx.x == 0) {
        float s = 0.0f;
#pragma unroll
        for (int i = 0; i < 8; ++i) s += sm[i];
        norm2[k] = s;
    }
}

extern "C" void kernel_launch(void* const* d_in, const int* in_sizes, int n_in,
                              void* d_out, int out_size, void* d_ws, size_t ws_size,
                              hipStream_t stream) {
    const float* W   = (const float*)d_in[0];  // (K, V, 2) fp32
    const float* Ps  = (const float*)d_in[1];  // (B, WD) fp32
    const float* pos = (const float*)d_in[2];  // (B, WD) fp32
    const int*   ids = (const int*)d_in[3];    // (B, WD) int32

    float* out = (float*)d_out;                // float32[2049]

    // ws layout (8B alignment first)
    char* p = (char*)d_ws;
    unsigned long long* amax = (unsigned long long*)p;  p += (size_t)BD * 8;
    float2*       cst     = (float2*)p;                 p += (size_t)WDIM * BD * 8;
    unsigned int* idp     = (unsigned int*)p;           p += (size_t)(WDIM / 2) * BD * 4;
    float*        norm2   = (float*)p;                  p += KD * 4;
    float*        contrib = (float*)p;                  p += BD * 4;
    int*          mu_int  = (int*)p;                    p += BD * 4;
    const size_t need = (size_t)(p - (char*)d_ws);

    if (ws_size >= need) {
        prep_kernel<<<(BD + 255) / 256, 256, 0, stream>>>(pos, ids, cst, idp);
        zero64_kernel<<<(BD + 255) / 256, 256, 0, stream>>>(amax);
        row_kernel<<<KD, 1024, 0, stream>>>(W, idp, cst, norm2, amax);
        decode_kernel<<<(BD + 255) / 256, 256, 0, stream>>>(amax, out, mu_int);
    } else {
        scores_kernel_fb<<<BD, 1024, 0, stream>>>(W, pos, ids, out, mu_int);
        norm_kernel_fb<<<KD, 512, 0, stream>>>(W, norm2);
    }
    e_kernel<<<BD, 64, 0, stream>>>(W, Ps, pos, ids, mu_int, norm2, contrib);
    finalize_kernel<<<1, 256, 0, stream>>>(contrib, out);
}